// Round 5
// baseline (589.224 us; speedup 1.0000x reference)
//
#include <hip/hip_runtime.h>

// ClusteringLoss on MI355X — round 9 (= R7/R8 resubmit; both prior benches
// died with "MI355X container failed twice" = broker infra, no kernel
// verdict; kernel is launch-config-identical to R5 which ran fine).
// Timed region = 2x 1GiB workspace-poison fills (~320 us, harness-fixed)
// + cl_main + cl_final (~2 us). Only lever: cl_main (~62 us vs 46 us BW
// floor at 306 MiB / 6.7 TB/s).
// Change under test: software pipeline, prefetch distance 2. R5's loop
// loaded row i+1 and used it immediately (load->use in-iteration; ~900cy
// HBM latency vs ~800cy compute across 2 resident waves/SIMD -> latency
// marginally exposed every row). 3-buffer rotation (compile-time %3
// indices under full unroll -> registers, not scratch) issues row i+2's
// 18 loads before computing on rows i/i+1 issued one iteration earlier;
// compiler waitcnt becomes vmcnt(~18) instead of vmcnt(0).
// ~200 VGPR < 256 keeps 2 blocks/CU (512-block grid = exact fill, no tail).
// Predict cl_main 62 -> ~50 us, total ~373. Fallback if VGPR>=256: dist-1.

constexpr int Bsz  = 8;
constexpr int Kc   = 8;          // all 8 channels per block
constexpr int H    = 1024;
constexpr int W    = 1024;
constexpr int ROWS = 16;         // rows per block; halo overhead = 1/ROWS
constexpr int RB   = H / ROWS;   // 64 row-blocks per image
constexpr int TPB  = 256;        // thread covers 4 cols (float4); 256*4 = W
constexpr size_t CH = (size_t)H * W;  // channel stride in floats

#define GAMMA_F    10.0f
#define EPS_SQRT_F 1e-24f

struct Row {
    float4 I;
    float  Ir;
    float4 p[Kc];
    float  pr[Kc];
};

__device__ __forceinline__ void loadRow(Row& R, const float* __restrict__ Ib,
                                        const float* __restrict__ Pb,
                                        size_t rofs, int j0, int jr, bool edge) {
    R.I  = *(const float4*)(Ib + rofs + j0);
    R.Ir = edge ? Ib[rofs + jr] : 0.0f;
    const float* p0 = Pb + rofs;          // channel k at p0 + k*CH
#pragma unroll
    for (int k = 0; k < Kc; ++k) {
        R.p[k]  = *(const float4*)(p0 + (size_t)k * CH + j0);
        R.pr[k] = edge ? p0[(size_t)k * CH + jr] : 0.0f;
    }
}

__device__ __forceinline__ float wedge(float c, float dn, float rt,
                                       float inv_sx, float inv_sy, float smin) {
    float dx = (dn - c) * inv_sx;
    float dy = (rt - c) * inv_sy;
    float gn2 = dx * dx + dy * dy;
    float g = sqrtf(fmaxf(gn2, EPS_SQRT_F));
    return 1.0f / (1.0f + GAMMA_F * g * smin);
}

__device__ __forceinline__ void accum(float pc, float pd, float pr, float w,
                                      float& nom, float& den) {
    float lap = (pd - pc) + (pr - pc);          // p_xp + p_yp
    nom = fmaf(pc, fmaf(w, lap, pc), nom);      // pc*(pc + w*lap)
    den = fmaf(pc, fmaf(2.0f, w, 1.0f), den);   // pc*(1 + 2w)
}

__device__ __forceinline__ void step(const Row& cur, const Row& nxt, bool edge,
                                     float inv_sx, float inv_sy, float smin,
                                     float* nom, float* den) {
    // right neighbor of cur.I.w: next lane's cur.I.x; lane 63 uses halo reg
    float Irt = __shfl_down(cur.I.x, 1, 64);
    if (edge) Irt = cur.Ir;

    const float w0 = wedge(cur.I.x, nxt.I.x, cur.I.y, inv_sx, inv_sy, smin);
    const float w1 = wedge(cur.I.y, nxt.I.y, cur.I.z, inv_sx, inv_sy, smin);
    const float w2 = wedge(cur.I.z, nxt.I.z, cur.I.w, inv_sx, inv_sy, smin);
    const float w3 = wedge(cur.I.w, nxt.I.w, Irt,     inv_sx, inv_sy, smin);

#pragma unroll
    for (int k = 0; k < Kc; ++k) {
        float prt = __shfl_down(cur.p[k].x, 1, 64);
        if (edge) prt = cur.pr[k];

        accum(cur.p[k].x, nxt.p[k].x, cur.p[k].y, w0, nom[k], den[k]);
        accum(cur.p[k].y, nxt.p[k].y, cur.p[k].z, w1, nom[k], den[k]);
        accum(cur.p[k].z, nxt.p[k].z, cur.p[k].w, w2, nom[k], den[k]);
        accum(cur.p[k].w, nxt.p[k].w, prt,        w3, nom[k], den[k]);
    }
}

__global__ __launch_bounds__(TPB) void cl_main(const float* __restrict__ I,
                                               const float* __restrict__ spacing,
                                               const float* __restrict__ P,
                                               float2* __restrict__ ws) {
    const int t    = threadIdx.x;
    const int lane = t & 63;
    const int j0   = t * 4;
    const int b    = blockIdx.y;
    const int r0   = blockIdx.x * ROWS;

    const float sx = spacing[0], sy = spacing[1];
    const float inv_sx = 1.0f / sx, inv_sy = 1.0f / sy;
    const float smin = fminf(sx, sy);

    const int jr = (j0 + 4 < W) ? (j0 + 4) : (W - 1);  // lane-63 halo col
    const bool edge = (lane == 63);

    const float* Ib = I + (size_t)b * CH;
    const float* Pb = P + (size_t)b * Kc * CH;

    float nom[Kc], den[Kc];
#pragma unroll
    for (int k = 0; k < Kc; ++k) { nom[k] = 0.0f; den[k] = 0.0f; }

    // ---- 3-buffer rotating pipeline, prefetch distance 2 ----
    Row buf[3];
    {
        const int i1 = (r0 + 1 < H) ? (r0 + 1) : (H - 1);
        loadRow(buf[0], Ib, Pb, (size_t)r0 * W, j0, jr, edge);
        loadRow(buf[1], Ib, Pb, (size_t)i1 * W, j0, jr, edge);
    }

#pragma unroll
    for (int ii = 0; ii < ROWS; ++ii) {
        if (ii + 2 <= ROWS) {           // compile-time under full unroll
            int ipf = r0 + ii + 2;
            if (ipf > H - 1) ipf = H - 1;
            loadRow(buf[(ii + 2) % 3], Ib, Pb, (size_t)ipf * W, j0, jr, edge);
        }
        step(buf[ii % 3], buf[(ii + 1) % 3], edge,
             inv_sx, inv_sy, smin, nom, den);
    }

    // ---- reduction: wave shuffle -> LDS -> per-block slot write ----
    __shared__ float red[4][2 * Kc];
    const int wave = t >> 6;

#pragma unroll
    for (int k = 0; k < Kc; ++k) {
        float n = nom[k], d = den[k];
#pragma unroll
        for (int off = 32; off > 0; off >>= 1) {
            n += __shfl_down(n, off, 64);
            d += __shfl_down(d, off, 64);
        }
        if (lane == 0) {
            red[wave][k]      = n;
            red[wave][Kc + k] = d;
        }
    }
    __syncthreads();

    if (t < Kc) {
        const int k = t;
        float n = red[0][k] + red[1][k] + red[2][k] + red[3][k];
        float d = red[0][Kc + k] + red[1][Kc + k] + red[2][Kc + k] + red[3][Kc + k];
        // slot layout: ((b*RB + rowblock)*Kc + k)
        ws[((size_t)b * RB + blockIdx.x) * Kc + k] = make_float2(n, d);
    }
}

// 512 threads: 8 partial-summers per (b,k) accumulator over 64 row-blocks.
__global__ __launch_bounds__(512) void cl_final(const float2* __restrict__ ws,
                                                float* __restrict__ out) {
    const int t    = threadIdx.x;
    const int acc  = t & 63;        // b = acc>>3, k = acc&7
    const int part = t >> 6;        // 0..7
    const int b = acc >> 3, k = acc & 7;

    double n = 0.0, d = 0.0;
#pragma unroll
    for (int r = part; r < RB; r += 8) {
        const float2 v = ws[((size_t)b * RB + r) * Kc + k];
        n += (double)v.x;
        d += (double)v.y;
    }

    __shared__ double sn[64][8], sd[64][8];
    sn[acc][part] = n;
    sd[acc][part] = d;
    __syncthreads();

    if (t < 64) {
        double nn = 0.0, dd = 0.0;
#pragma unroll
        for (int p = 0; p < 8; ++p) { nn += sn[t][p]; dd += sd[t][p]; }
        double c = nn / dd;
#pragma unroll
        for (int off = 32; off > 0; off >>= 1) c += __shfl_down(c, off, 64);
        if (t == 0) out[0] = (float)((double)(Bsz * Kc) - c);
    }
}

extern "C" void kernel_launch(void* const* d_in, const int* in_sizes, int n_in,
                              void* d_out, int out_size, void* d_ws, size_t ws_size,
                              hipStream_t stream) {
    const float* I       = (const float*)d_in[0];  // (8,1,1024,1024)
    const float* spacing = (const float*)d_in[1];  // (2,)
    const float* P       = (const float*)d_in[2];  // (8,8,1024,1024)
    float* out = (float*)d_out;
    float2* ws = (float2*)d_ws;  // 8*64*8 float2 slots = 32 KiB, all overwritten

    dim3 grid(RB, Bsz);
    cl_main<<<grid, TPB, 0, stream>>>(I, spacing, P, ws);
    cl_final<<<1, 512, 0, stream>>>(ws, out);
}

// Round 7
// 383.456 us; speedup vs baseline: 1.5366x; 1.5366x over previous
//
#include <hip/hip_runtime.h>

// ClusteringLoss on MI355X — round 11 (= R10 resubmit; R10 died with
// "MI355X container failed twice" = broker infra — this exact kernel
// already benched 382.5 us as R4 in round 0, so no kernel-side cause).
// Ledger:
//  - Timed region = 2x 1GiB harness poison fills (~320 us @ 85% HBM peak,
//    untouchable) + cl_main (~60 us) + cl_final (~2 us).
//  - R5 (KPB=8, clustered loads): neutral (384.8).
//  - R6 (ROWS=8 + XCD swizzle): -28 us regression (3 blocks/CU tail).
//  - R9 (distance-2 Row buf[3] pipeline): VGPR=256 + 200 MB scratch spill
//    (struct-array defeated SROA) -> cl_main 326 us. Reverted.
//  - Latency theory dead: cl_main VALUBusy ~5%, outstanding-load capacity
//    >> per-SIMD HBM share; it is BW-bound at ~4.9 TB/s (~75% of stream
//    ceiling; residual = DRAM efficiency of multi-stream reads, not
//    hideable latency). Structural floor ~370-377 us; R4 is within ~3%.

constexpr int Bsz  = 8;
constexpr int Kc   = 8;
constexpr int KPB  = 4;          // channels per block (K split in 2)
constexpr int H    = 1024;
constexpr int W    = 1024;
constexpr int ROWS = 16;         // rows per block; halo overhead = 1/ROWS
constexpr int RB   = H / ROWS;   // 64 row-blocks per image
constexpr int TPB  = 256;        // thread covers 4 cols (float4); 256*4 = W

#define GAMMA_F    10.0f
#define EPS_SQRT_F 1e-24f

__device__ __forceinline__ float wedge(float c, float dn, float rt,
                                       float inv_sx, float inv_sy, float smin) {
    float dx = (dn - c) * inv_sx;
    float dy = (rt - c) * inv_sy;
    float gn2 = dx * dx + dy * dy;
    float g = sqrtf(fmaxf(gn2, EPS_SQRT_F));
    return 1.0f / (1.0f + GAMMA_F * g * smin);
}

__device__ __forceinline__ void accum(float pc, float pd, float pr, float w,
                                      float& nom, float& den) {
    float lap = (pd - pc) + (pr - pc);          // p_xp + p_yp
    nom = fmaf(pc, fmaf(w, lap, pc), nom);      // pc*(pc + w*lap)
    den = fmaf(pc, fmaf(2.0f, w, 1.0f), den);   // pc*(1 + 2w)
}

__global__ __launch_bounds__(TPB) void cl_main(const float* __restrict__ I,
                                               const float* __restrict__ spacing,
                                               const float* __restrict__ P,
                                               float2* __restrict__ ws) {
    const int t    = threadIdx.x;
    const int lane = t & 63;
    const int j0   = t * 4;
    const int b    = blockIdx.y;
    const int kh   = blockIdx.z;             // K half: channels kh*4 .. kh*4+3
    const int r0   = blockIdx.x * ROWS;

    const float sx = spacing[0], sy = spacing[1];
    const float inv_sx = 1.0f / sx, inv_sy = 1.0f / sy;
    const float smin = fminf(sx, sy);

    const int jr = (j0 + 4 < W) ? (j0 + 4) : (W - 1);  // lane-63 halo col
    const bool edge = (lane == 63);

    const float* Ib = I + (size_t)b * H * W;
    const float* Pk0 = P + ((size_t)(b * Kc + kh * KPB)) * H * W;

    // ---- register carry: current row of I and 4 channels of p ----
    float4 cI  = *(const float4*)(Ib + (size_t)r0 * W + j0);
    float  cIr = edge ? Ib[(size_t)r0 * W + jr] : 0.0f;
    float4 cp[KPB];
    float  cpr[KPB];
#pragma unroll
    for (int k = 0; k < KPB; ++k) {
        const float* Pk = Pk0 + (size_t)k * H * W;
        cp[k]  = *(const float4*)(Pk + (size_t)r0 * W + j0);
        cpr[k] = edge ? Pk[(size_t)r0 * W + jr] : 0.0f;
    }

    float nom[KPB], den[KPB];
#pragma unroll
    for (int k = 0; k < KPB; ++k) { nom[k] = 0.0f; den[k] = 0.0f; }

#pragma unroll 1
    for (int ii = 0; ii < ROWS; ++ii) {
        const int i = r0 + ii;
        const int inext = (i + 1 < H) ? (i + 1) : (H - 1);
        const size_t rn = (size_t)inext * W;

        const float4 nI  = *(const float4*)(Ib + rn + j0);
        const float  nIr = edge ? Ib[rn + jr] : 0.0f;

        // right neighbor of cI.w: next lane's cI.x; lane 63 uses carried halo
        float Irt = __shfl_down(cI.x, 1, 64);
        if (edge) Irt = cIr;

        const float w0 = wedge(cI.x, nI.x, cI.y, inv_sx, inv_sy, smin);
        const float w1 = wedge(cI.y, nI.y, cI.z, inv_sx, inv_sy, smin);
        const float w2 = wedge(cI.z, nI.z, cI.w, inv_sx, inv_sy, smin);
        const float w3 = wedge(cI.w, nI.w, Irt,  inv_sx, inv_sy, smin);

#pragma unroll
        for (int k = 0; k < KPB; ++k) {
            const float* Pk = Pk0 + (size_t)k * H * W;
            const float4 np  = *(const float4*)(Pk + rn + j0);
            const float  npr = edge ? Pk[rn + jr] : 0.0f;

            float prt = __shfl_down(cp[k].x, 1, 64);
            if (edge) prt = cpr[k];

            accum(cp[k].x, np.x, cp[k].y, w0, nom[k], den[k]);
            accum(cp[k].y, np.y, cp[k].z, w1, nom[k], den[k]);
            accum(cp[k].z, np.z, cp[k].w, w2, nom[k], den[k]);
            accum(cp[k].w, np.w, prt,     w3, nom[k], den[k]);

            cp[k]  = np;
            cpr[k] = npr;
        }
        cI  = nI;
        cIr = nIr;
    }

    // ---- reduction: wave shuffle -> LDS -> per-block slot write ----
    __shared__ float red[4][2 * KPB];
    const int wave = t >> 6;

#pragma unroll
    for (int k = 0; k < KPB; ++k) {
        float n = nom[k], d = den[k];
#pragma unroll
        for (int off = 32; off > 0; off >>= 1) {
            n += __shfl_down(n, off, 64);
            d += __shfl_down(d, off, 64);
        }
        if (lane == 0) {
            red[wave][k]       = n;
            red[wave][KPB + k] = d;
        }
    }
    __syncthreads();

    if (t < KPB) {
        const int k = t;
        float n = red[0][k] + red[1][k] + red[2][k] + red[3][k];
        float d = red[0][KPB + k] + red[1][KPB + k] + red[2][KPB + k] + red[3][KPB + k];
        // slot layout: (((b*2 + kh)*RB + rowblock)*KPB + k)
        ws[(((size_t)(b * 2 + kh) * RB) + blockIdx.x) * KPB + k] = make_float2(n, d);
    }
}

// 512 threads: 8 partial-summers per (b,k) accumulator over 64 row-blocks.
__global__ __launch_bounds__(512) void cl_final(const float2* __restrict__ ws,
                                                float* __restrict__ out) {
    const int t    = threadIdx.x;
    const int acc  = t & 63;        // b = acc>>3, k = acc&7
    const int part = t >> 6;        // 0..7
    const int b = acc >> 3, k = acc & 7;
    const int kh = k >> 2, kk = k & 3;

    double n = 0.0, d = 0.0;
#pragma unroll
    for (int r = part; r < RB; r += 8) {
        const float2 v = ws[(((size_t)(b * 2 + kh) * RB) + r) * KPB + kk];
        n += (double)v.x;
        d += (double)v.y;
    }

    __shared__ double sn[64][8], sd[64][8];
    sn[acc][part] = n;
    sd[acc][part] = d;
    __syncthreads();

    if (t < 64) {
        double nn = 0.0, dd = 0.0;
#pragma unroll
        for (int p = 0; p < 8; ++p) { nn += sn[t][p]; dd += sd[t][p]; }
        double c = nn / dd;
#pragma unroll
        for (int off = 32; off > 0; off >>= 1) c += __shfl_down(c, off, 64);
        if (t == 0) out[0] = (float)((double)(Bsz * Kc) - c);
    }
}

extern "C" void kernel_launch(void* const* d_in, const int* in_sizes, int n_in,
                              void* d_out, int out_size, void* d_ws, size_t ws_size,
                              hipStream_t stream) {
    const float* I       = (const float*)d_in[0];  // (8,1,1024,1024)
    const float* spacing = (const float*)d_in[1];  // (2,)
    const float* P       = (const float*)d_in[2];  // (8,8,1024,1024)
    float* out = (float*)d_out;
    float2* ws = (float2*)d_ws;  // 8*2*64*4 float2 slots = 32 KiB, all overwritten

    dim3 grid(RB, Bsz, 2);
    cl_main<<<grid, TPB, 0, stream>>>(I, spacing, P, ws);
    cl_final<<<1, 512, 0, stream>>>(ws, out);
}